// Round 3
// baseline (531.005 us; speedup 1.0000x reference)
//
#include <hip/hip_runtime.h>
#include <cstdint>
#include <cstddef>

typedef unsigned short ushort_t;
typedef unsigned short ushort8 __attribute__((ext_vector_type(8)));
typedef __bf16 bf16x8 __attribute__((ext_vector_type(8)));
typedef float floatx4 __attribute__((ext_vector_type(4)));

#define N_TOK 8192
#define CDIM 1024
#define NEXP 8

__device__ __forceinline__ float bf2f(ushort_t h) {
  union { unsigned int u; float f; } v; v.u = ((unsigned int)h) << 16; return v.f;
}
__device__ __forceinline__ ushort_t f2bf(float f) {
  union { float f; unsigned int u; } v; v.f = f;
  unsigned int r = v.u + 0x7fffu + ((v.u >> 16) & 1u);
  return (ushort_t)(r >> 16);
}

// Input-dtype probe: f32 data viewed as ushorts has mantissa halves whose
// bf16 exponent field is uniform-random; bf16 N(0,1) data never leaves
// exp in [0x31,0xBF]. Deterministic per input -> graph-safe.
__global__ void detect_init_kernel(const ushort_t* __restrict__ x,
                                   int* __restrict__ flag,
                                   int* __restrict__ cnt) {
  int tid = threadIdx.x;  // 128 threads
  ushort_t u = x[tid];
  int ex = (u >> 7) & 0xFF;
  int crazy = (ex >= 0xC0 || ex <= 0x30) ? 1 : 0;
  int total = __syncthreads_count(crazy);
  if (tid == 0) flag[0] = (total >= 16) ? 1 : 0;
  if (tid < NEXP) cnt[tid] = 0;
}

// One wave per token: logits at NATIVE precision (selection must match ref),
// top-2 (ties -> lower index), softmax over 2, scatter slot=t*2+k.
__global__ void router_kernel(const void* __restrict__ xv,
                              const void* __restrict__ rwv,
                              const int* __restrict__ flag,
                              int* __restrict__ cnt,
                              int* __restrict__ slots,
                              float* __restrict__ prob) {
  int isf32 = flag[0];
  int wid = threadIdx.x >> 6;
  int lane = threadIdx.x & 63;
  int t = blockIdx.x * 4 + wid;

  float acc[NEXP];
#pragma unroll
  for (int e = 0; e < NEXP; e++) acc[e] = 0.f;

  if (isf32) {
    const float* xr = (const float*)xv + (size_t)t * CDIM;
    const float* rw = (const float*)rwv;
#pragma unroll
    for (int half = 0; half < 2; half++) {
      int base = (lane + half * 64) * 8;
      floatx4 x0 = *(const floatx4*)(xr + base);
      floatx4 x1 = *(const floatx4*)(xr + base + 4);
#pragma unroll
      for (int e = 0; e < NEXP; e++) {
        floatx4 w0 = *(const floatx4*)(rw + e * CDIM + base);
        floatx4 w1 = *(const floatx4*)(rw + e * CDIM + base + 4);
        acc[e] += x0[0]*w0[0] + x0[1]*w0[1] + x0[2]*w0[2] + x0[3]*w0[3]
                + x1[0]*w1[0] + x1[1]*w1[1] + x1[2]*w1[2] + x1[3]*w1[3];
      }
    }
  } else {
    const ushort_t* xr = (const ushort_t*)xv + (size_t)t * CDIM;
    const ushort_t* rw = (const ushort_t*)rwv;
#pragma unroll
    for (int half = 0; half < 2; half++) {
      int base = (lane + half * 64) * 8;
      ushort8 xu = *(const ushort8*)(xr + base);
#pragma unroll
      for (int e = 0; e < NEXP; e++) {
        ushort8 wu = *(const ushort8*)(rw + e * CDIM + base);
#pragma unroll
        for (int i = 0; i < 8; i++) acc[e] += bf2f(xu[i]) * bf2f(wu[i]);
      }
    }
  }

#pragma unroll
  for (int e = 0; e < NEXP; e++) {
#pragma unroll
    for (int off = 32; off > 0; off >>= 1) acc[e] += __shfl_xor(acc[e], off);
  }

  if (lane == 0) {
    int e0 = 0; float l0 = acc[0];
#pragma unroll
    for (int e = 1; e < NEXP; e++) if (acc[e] > l0) { l0 = acc[e]; e0 = e; }
    int e1 = (e0 == 0) ? 1 : 0; float l1 = acc[e1];
#pragma unroll
    for (int e = 0; e < NEXP; e++) {
      if (e != e0 && acc[e] > l1) { l1 = acc[e]; e1 = e; }
    }
    float p0 = 1.f / (1.f + __expf(l1 - l0));  // l0 = max -> stable
    float p1 = 1.f - p0;
    int pos0 = atomicAdd(&cnt[e0], 1) & (N_TOK - 1);
    slots[e0 * N_TOK + pos0] = t * 2;
    int pos1 = atomicAdd(&cnt[e1], 1) & (N_TOK - 1);
    slots[e1 * N_TOK + pos1] = t * 2 + 1;
    prob[t * 2] = p0;
    prob[t * 2 + 1] = p1;
  }
}

// Transpose (+convert to bf16) 1024x1024: z<8 -> w1[z], else w2[z-8].
__global__ void transpose_kernel(const void* __restrict__ w1v,
                                 const void* __restrict__ w2v,
                                 const int* __restrict__ flag,
                                 ushort_t* __restrict__ w1T,
                                 ushort_t* __restrict__ w2T) {
  int isf32 = flag[0];
  int z = blockIdx.z;
  size_t moff = (size_t)(z & 7) << 20;
  const void* srcv = (z < 8) ? w1v : w2v;
  ushort_t* dst = ((z < 8) ? w1T : w2T) + moff;

  __shared__ __align__(16) ushort_t tile[64][72];
  int t = threadIdx.x;
  int R0 = blockIdx.y * 64, C0 = blockIdx.x * 64;
  int r = t >> 2, cb = (t & 3) * 16;
  if (isf32) {
    const float* sp = (const float*)srcv + moff + (size_t)(R0 + r) * 1024 + C0 + cb;
    ushort8 o0, o1;
#pragma unroll
    for (int q = 0; q < 2; q++) {
      floatx4 f = *(const floatx4*)(sp + q * 4);
#pragma unroll
      for (int i = 0; i < 4; i++) o0[q * 4 + i] = f2bf(f[i]);
    }
#pragma unroll
    for (int q = 0; q < 2; q++) {
      floatx4 f = *(const floatx4*)(sp + 8 + q * 4);
#pragma unroll
      for (int i = 0; i < 4; i++) o1[q * 4 + i] = f2bf(f[i]);
    }
    *(ushort8*)&tile[r][cb] = o0;
    *(ushort8*)&tile[r][cb + 8] = o1;
  } else {
    const ushort_t* sp = (const ushort_t*)srcv + moff + (size_t)(R0 + r) * 1024 + C0 + cb;
    *(ushort8*)&tile[r][cb] = *(const ushort8*)sp;
    *(ushort8*)&tile[r][cb + 8] = *(const ushort8*)(sp + 8);
  }
  __syncthreads();
  int d = t >> 2, rb = (t & 3) * 16;
  ushort8 o0, o1;
#pragma unroll
  for (int j = 0; j < 8; j++) { o0[j] = tile[rb + j][d]; o1[j] = tile[rb + 8 + j][d]; }
  ushort_t* dp = dst + (size_t)(C0 + d) * 1024 + R0 + rb;
  *(ushort8*)dp = o0;
  *(ushort8*)(dp + 8) = o1;
}

// Grouped GEMM, 128x128 tile, BK=64, mfma_f32_16x16x32_bf16, 4 waves (2x2).
// MODE 0: hidden[slot] = relu(x[slot>>1] @ w1T[e]^T)^2   (A native dtype)
// MODE 1: oslots[slot] = prob[slot] * (hidden[slot] @ w2T[e]^T)  (A bf16)
template <int MODE>
__global__ __launch_bounds__(256) void moe_gemm(const void* __restrict__ Asrc,
                                                const ushort_t* __restrict__ BT,
                                                ushort_t* __restrict__ Out,
                                                const int* __restrict__ cnt,
                                                const int* __restrict__ slots,
                                                const float* __restrict__ prob,
                                                const int* __restrict__ flag) {
  int isf32 = (MODE == 0) ? flag[0] : 0;
  int e = blockIdx.z;
  int M = cnt[e];
  M = (M > N_TOK) ? N_TOK : M;
  int m0 = blockIdx.y * 128;
  if (m0 >= M) return;
  int n0 = blockIdx.x * 128;

  __shared__ __align__(16) ushort_t As[128][72];
  __shared__ __align__(16) ushort_t Bs[128][72];
  __shared__ int srow[128];

  int tid = threadIdx.x;
  if (tid < 128) {
    int gm = m0 + tid;
    int gi = (gm < M) ? gm : (M - 1);
    srow[tid] = slots[e * N_TOK + gi] & (2 * N_TOK - 1);
  }
  __syncthreads();

  int ar = tid >> 1;
  int akc = (tid & 1) * 4;
  int s_a = srow[ar];
  const ushort_t* arow_b =
      (MODE == 0) ? ((const ushort_t*)Asrc + (size_t)(s_a >> 1) * CDIM)
                  : ((const ushort_t*)Asrc + (size_t)s_a * CDIM);
  const float* arow_f = (const float*)Asrc + (size_t)(s_a >> 1) * CDIM;
  const ushort_t* brow = BT + ((size_t)e << 20) + (size_t)(n0 + ar) * 1024;

  int wid = tid >> 6;
  int lane = tid & 63;
  int wm = (wid >> 1) * 64;
  int wn = (wid & 1) * 64;
  int qd = lane >> 4;
  int ln = lane & 15;

  floatx4 zero = {0.f, 0.f, 0.f, 0.f};
  floatx4 acc[4][4];
#pragma unroll
  for (int i = 0; i < 4; i++)
#pragma unroll
    for (int j = 0; j < 4; j++) acc[i][j] = zero;

  for (int k0 = 0; k0 < 1024; k0 += 64) {
    ushort8 a0, a1, a2, a3;
    if (MODE == 0 && isf32) {
      const float* ap = arow_f + k0 + akc * 8;
      floatx4 f[8];
#pragma unroll
      for (int q = 0; q < 8; q++) f[q] = *(const floatx4*)(ap + q * 4);
#pragma unroll
      for (int i = 0; i < 4; i++) {
        a0[i] = f2bf(f[0][i]); a0[i + 4] = f2bf(f[1][i]);
        a1[i] = f2bf(f[2][i]); a1[i + 4] = f2bf(f[3][i]);
        a2[i] = f2bf(f[4][i]); a2[i + 4] = f2bf(f[5][i]);
        a3[i] = f2bf(f[6][i]); a3[i + 4] = f2bf(f[7][i]);
      }
    } else {
      const ushort_t* ap = arow_b + k0 + akc * 8;
      a0 = *(const ushort8*)(ap);
      a1 = *(const ushort8*)(ap + 8);
      a2 = *(const ushort8*)(ap + 16);
      a3 = *(const ushort8*)(ap + 24);
    }
    const ushort_t* bp = brow + k0 + akc * 8;
    ushort8 b0 = *(const ushort8*)(bp);
    ushort8 b1 = *(const ushort8*)(bp + 8);
    ushort8 b2 = *(const ushort8*)(bp + 16);
    ushort8 b3 = *(const ushort8*)(bp + 24);
    __syncthreads();
    *(ushort8*)&As[ar][akc * 8] = a0;
    *(ushort8*)&As[ar][akc * 8 + 8] = a1;
    *(ushort8*)&As[ar][akc * 8 + 16] = a2;
    *(ushort8*)&As[ar][akc * 8 + 24] = a3;
    *(ushort8*)&Bs[ar][akc * 8] = b0;
    *(ushort8*)&Bs[ar][akc * 8 + 8] = b1;
    *(ushort8*)&Bs[ar][akc * 8 + 16] = b2;
    *(ushort8*)&Bs[ar][akc * 8 + 24] = b3;
    __syncthreads();
#pragma unroll
    for (int ks = 0; ks < 2; ks++) {
      int koff = ks * 32 + qd * 8;
      bf16x8 afr[4], bfr[4];
#pragma unroll
      for (int i = 0; i < 4; i++) afr[i] = *(const bf16x8*)&As[wm + i * 16 + ln][koff];
#pragma unroll
      for (int j = 0; j < 4; j++) bfr[j] = *(const bf16x8*)&Bs[wn + j * 16 + ln][koff];
#pragma unroll
      for (int i = 0; i < 4; i++)
#pragma unroll
        for (int j = 0; j < 4; j++)
          acc[i][j] = __builtin_amdgcn_mfma_f32_16x16x32_bf16(afr[i], bfr[j], acc[i][j], 0, 0, 0);
    }
  }

  // C/D layout: col = lane&15, row = (lane>>4)*4 + reg  [m89]
#pragma unroll
  for (int i = 0; i < 4; i++) {
#pragma unroll
    for (int r = 0; r < 4; r++) {
      int rl = wm + i * 16 + qd * 4 + r;
      int gm = m0 + rl;
      if (gm >= M) continue;
      int s = srow[rl];
      float p = (MODE == 1) ? prob[s] : 0.f;
      ushort_t* orow = Out + (size_t)s * 1024 + n0 + wn + ln;
#pragma unroll
      for (int j = 0; j < 4; j++) {
        float v = acc[i][j][r];
        if (MODE == 0) { v = fmaxf(v, 0.f); v = v * v; }
        else v *= p;
        orow[j * 16] = f2bf(v);
      }
    }
  }
}

// out (FLOAT32) [t][c] = oslots[2t][c] + oslots[2t+1][c]
__global__ void combine_kernel(const ushort_t* __restrict__ oslots,
                               float* __restrict__ out) {
  int idx = (blockIdx.x * 256 + threadIdx.x) * 8;
  int t = idx >> 10;
  int c = idx & 1023;
  const ushort_t* r0 = oslots + ((size_t)t * 2) * 1024 + c;
  const ushort_t* r1 = r0 + 1024;
  ushort8 a = *(const ushort8*)r0;
  ushort8 b = *(const ushort8*)r1;
  floatx4 o0, o1;
#pragma unroll
  for (int i = 0; i < 4; i++) o0[i] = bf2f(a[i]) + bf2f(b[i]);
#pragma unroll
  for (int i = 0; i < 4; i++) o1[i] = bf2f(a[4 + i]) + bf2f(b[4 + i]);
  *(floatx4*)(out + idx) = o0;
  *(floatx4*)(out + idx + 4) = o1;
}

extern "C" void kernel_launch(void* const* d_in, const int* in_sizes, int n_in,
                              void* d_out, int out_size, void* d_ws, size_t ws_size,
                              hipStream_t stream) {
  const void* x  = d_in[0];
  const void* rw = d_in[1];
  const void* w1 = d_in[2];
  const void* w2 = d_in[3];
  float* out = (float*)d_out;
  char* ws = (char*)d_ws;

  int* cnt  = (int*)(ws + 0);                       // 32 B
  int* flag = (int*)(ws + 64);                      // 4 B
  int* slots = (int*)(ws + 1024);                   // 256 KiB
  float* prob = (float*)(ws + 263168);              // 64 KiB
  ushort_t* hidden = (ushort_t*)(ws + 524288);      // 32 MiB
  ushort_t* w2T = (ushort_t*)(ws + 34078720);       // 16 MiB
  ushort_t* w1T = (ushort_t*)(ws + 50855936);       // 16 MiB (dead after gemm0)
  ushort_t* oslots = (ushort_t*)(ws + 50855936);    // 32 MiB, aliases w1T
  // high-water: 84,410,368 B ~ 80.5 MiB

  detect_init_kernel<<<1, 128, 0, stream>>>((const ushort_t*)x, flag, cnt);
  router_kernel<<<N_TOK / 4, 256, 0, stream>>>(x, rw, flag, cnt, slots, prob);
  transpose_kernel<<<dim3(16, 16, 16), 256, 0, stream>>>(w1, w2, flag, w1T, w2T);
  moe_gemm<0><<<dim3(8, 64, 8), 256, 0, stream>>>(x, w1T, hidden, cnt, slots, prob, flag);
  moe_gemm<1><<<dim3(8, 64, 8), 256, 0, stream>>>(hidden, w2T, oslots, cnt, slots, prob, flag);
  combine_kernel<<<4096, 256, 0, stream>>>(oslots, out);
}

// Round 4
// 358.678 us; speedup vs baseline: 1.4805x; 1.4805x over previous
//
#include <hip/hip_runtime.h>
#include <cstdint>
#include <cstddef>

typedef unsigned short ushort_t;
typedef unsigned short ushort8 __attribute__((ext_vector_type(8)));
typedef __bf16 bf16x8 __attribute__((ext_vector_type(8)));
typedef float floatx4 __attribute__((ext_vector_type(4)));

#define N_TOK 8192
#define CDIM 1024
#define NEXP 8

__device__ __forceinline__ float bf2f(ushort_t h) {
  union { unsigned int u; float f; } v; v.u = ((unsigned int)h) << 16; return v.f;
}
__device__ __forceinline__ ushort_t f2bf(float f) {
  union { float f; unsigned int u; } v; v.f = f;
  unsigned int r = v.u + 0x7fffu + ((v.u >> 16) & 1u);
  return (ushort_t)(r >> 16);
}

// Input-dtype probe (f32 vs bf16) + zero the expert counters.
__global__ void detect_init_kernel(const ushort_t* __restrict__ x,
                                   int* __restrict__ flag,
                                   int* __restrict__ cnt) {
  int tid = threadIdx.x;  // 128 threads
  ushort_t u = x[tid];
  int ex = (u >> 7) & 0xFF;
  int crazy = (ex >= 0xC0 || ex <= 0x30) ? 1 : 0;
  int total = __syncthreads_count(crazy);
  if (tid == 0) flag[0] = (total >= 16) ? 1 : 0;
  if (tid < NEXP) cnt[tid] = 0;
}

// One wave per token: logits at native precision, top-2 (ties->lower idx),
// softmax over 2. NO global atomics — writes tok_e[t] and probs only.
__global__ void router_compute(const void* __restrict__ xv,
                               const void* __restrict__ rwv,
                               const int* __restrict__ flag,
                               int* __restrict__ tok_e,
                               float* __restrict__ prob) {
  int isf32 = flag[0];
  int wid = threadIdx.x >> 6;
  int lane = threadIdx.x & 63;
  int t = blockIdx.x * 4 + wid;

  float acc[NEXP];
#pragma unroll
  for (int e = 0; e < NEXP; e++) acc[e] = 0.f;

  if (isf32) {
    const float* xr = (const float*)xv + (size_t)t * CDIM;
    const float* rw = (const float*)rwv;
#pragma unroll
    for (int half = 0; half < 2; half++) {
      int base = (lane + half * 64) * 8;
      floatx4 x0 = *(const floatx4*)(xr + base);
      floatx4 x1 = *(const floatx4*)(xr + base + 4);
#pragma unroll
      for (int e = 0; e < NEXP; e++) {
        floatx4 w0 = *(const floatx4*)(rw + e * CDIM + base);
        floatx4 w1 = *(const floatx4*)(rw + e * CDIM + base + 4);
        acc[e] += x0[0]*w0[0] + x0[1]*w0[1] + x0[2]*w0[2] + x0[3]*w0[3]
                + x1[0]*w1[0] + x1[1]*w1[1] + x1[2]*w1[2] + x1[3]*w1[3];
      }
    }
  } else {
    const ushort_t* xr = (const ushort_t*)xv + (size_t)t * CDIM;
    const ushort_t* rw = (const ushort_t*)rwv;
#pragma unroll
    for (int half = 0; half < 2; half++) {
      int base = (lane + half * 64) * 8;
      ushort8 xu = *(const ushort8*)(xr + base);
#pragma unroll
      for (int e = 0; e < NEXP; e++) {
        ushort8 wu = *(const ushort8*)(rw + e * CDIM + base);
#pragma unroll
        for (int i = 0; i < 8; i++) acc[e] += bf2f(xu[i]) * bf2f(wu[i]);
      }
    }
  }

#pragma unroll
  for (int e = 0; e < NEXP; e++) {
#pragma unroll
    for (int off = 32; off > 0; off >>= 1) acc[e] += __shfl_xor(acc[e], off);
  }

  if (lane == 0) {
    int e0 = 0; float l0 = acc[0];
#pragma unroll
    for (int e = 1; e < NEXP; e++) if (acc[e] > l0) { l0 = acc[e]; e0 = e; }
    int e1 = (e0 == 0) ? 1 : 0; float l1 = acc[e1];
#pragma unroll
    for (int e = 0; e < NEXP; e++) {
      if (e != e0 && acc[e] > l1) { l1 = acc[e]; e1 = e; }
    }
    float p0 = 1.f / (1.f + __expf(l1 - l0));  // l0 = max -> stable
    tok_e[t] = e0 | (e1 << 8);
    prob[t * 2] = p0;
    prob[t * 2 + 1] = 1.f - p0;
  }
}

// Build per-expert slot lists. 8 blocks x 1024 threads, 1024 tokens/block.
// LDS histogram -> 8 global atomics/block (64 total) -> conflict-free writes.
__global__ void scatter_kernel(const int* __restrict__ tok_e,
                               int* __restrict__ cnt,
                               int* __restrict__ slots) {
  __shared__ int lcnt[NEXP];
  __shared__ int gbase[NEXP];
  int tid = threadIdx.x;
  if (tid < NEXP) lcnt[tid] = 0;
  __syncthreads();
  int t = blockIdx.x * 1024 + tid;
  int ee = tok_e[t];
  int e0 = ee & 0xFF, e1 = (ee >> 8) & 0xFF;
  int lofs0 = atomicAdd(&lcnt[e0], 1);
  int lofs1 = atomicAdd(&lcnt[e1], 1);
  __syncthreads();
  if (tid < NEXP) gbase[tid] = atomicAdd(&cnt[tid], lcnt[tid]);
  __syncthreads();
  slots[e0 * N_TOK + gbase[e0] + lofs0] = t * 2;
  slots[e1 * N_TOK + gbase[e1] + lofs1] = t * 2 + 1;
}

// Transpose (+convert to bf16) 1024x1024: z<8 -> w1[z], else w2[z-8].
__global__ void transpose_kernel(const void* __restrict__ w1v,
                                 const void* __restrict__ w2v,
                                 const int* __restrict__ flag,
                                 ushort_t* __restrict__ w1T,
                                 ushort_t* __restrict__ w2T) {
  int isf32 = flag[0];
  int z = blockIdx.z;
  size_t moff = (size_t)(z & 7) << 20;
  const void* srcv = (z < 8) ? w1v : w2v;
  ushort_t* dst = ((z < 8) ? w1T : w2T) + moff;

  __shared__ __align__(16) ushort_t tile[64][72];
  int t = threadIdx.x;
  int R0 = blockIdx.y * 64, C0 = blockIdx.x * 64;
  int r = t >> 2, cb = (t & 3) * 16;
  if (isf32) {
    const float* sp = (const float*)srcv + moff + (size_t)(R0 + r) * 1024 + C0 + cb;
    ushort8 o0, o1;
#pragma unroll
    for (int q = 0; q < 2; q++) {
      floatx4 f = *(const floatx4*)(sp + q * 4);
#pragma unroll
      for (int i = 0; i < 4; i++) o0[q * 4 + i] = f2bf(f[i]);
    }
#pragma unroll
    for (int q = 0; q < 2; q++) {
      floatx4 f = *(const floatx4*)(sp + 8 + q * 4);
#pragma unroll
      for (int i = 0; i < 4; i++) o1[q * 4 + i] = f2bf(f[i]);
    }
    *(ushort8*)&tile[r][cb] = o0;
    *(ushort8*)&tile[r][cb + 8] = o1;
  } else {
    const ushort_t* sp = (const ushort_t*)srcv + moff + (size_t)(R0 + r) * 1024 + C0 + cb;
    *(ushort8*)&tile[r][cb] = *(const ushort8*)sp;
    *(ushort8*)&tile[r][cb + 8] = *(const ushort8*)(sp + 8);
  }
  __syncthreads();
  int d = t >> 2, rb = (t & 3) * 16;
  ushort8 o0, o1;
#pragma unroll
  for (int j = 0; j < 8; j++) { o0[j] = tile[rb + j][d]; o1[j] = tile[rb + 8 + j][d]; }
  ushort_t* dp = dst + (size_t)(C0 + d) * 1024 + R0 + rb;
  *(ushort8*)dp = o0;
  *(ushort8*)(dp + 8) = o1;
}

// Grouped GEMM, 128x128 tile, BK=64, mfma_f32_16x16x32_bf16, 4 waves (2x2).
// MODE 0: hidden[slot] = relu(x[slot>>1] @ w1T[e]^T)^2   (A native dtype)
// MODE 1: oslots[slot] = prob[slot] * (hidden[slot] @ w2T[e]^T)  (A bf16)
template <int MODE>
__global__ __launch_bounds__(256) void moe_gemm(const void* __restrict__ Asrc,
                                                const ushort_t* __restrict__ BT,
                                                ushort_t* __restrict__ Out,
                                                const int* __restrict__ cnt,
                                                const int* __restrict__ slots,
                                                const float* __restrict__ prob,
                                                const int* __restrict__ flag) {
  int isf32 = (MODE == 0) ? flag[0] : 0;
  int e = blockIdx.z;
  int M = cnt[e];
  M = (M > N_TOK) ? N_TOK : M;
  int m0 = blockIdx.y * 128;
  if (m0 >= M) return;
  int n0 = blockIdx.x * 128;

  __shared__ __align__(16) ushort_t As[128][72];
  __shared__ __align__(16) ushort_t Bs[128][72];
  __shared__ int srow[128];

  int tid = threadIdx.x;
  if (tid < 128) {
    int gm = m0 + tid;
    int gi = (gm < M) ? gm : (M - 1);
    srow[tid] = slots[e * N_TOK + gi] & (2 * N_TOK - 1);
  }
  __syncthreads();

  int ar = tid >> 1;
  int akc = (tid & 1) * 4;
  int s_a = srow[ar];
  const ushort_t* arow_b =
      (MODE == 0) ? ((const ushort_t*)Asrc + (size_t)(s_a >> 1) * CDIM)
                  : ((const ushort_t*)Asrc + (size_t)s_a * CDIM);
  const float* arow_f = (const float*)Asrc + (size_t)(s_a >> 1) * CDIM;
  const ushort_t* brow = BT + ((size_t)e << 20) + (size_t)(n0 + ar) * 1024;

  int wid = tid >> 6;
  int lane = tid & 63;
  int wm = (wid >> 1) * 64;
  int wn = (wid & 1) * 64;
  int qd = lane >> 4;
  int ln = lane & 15;

  floatx4 zero = {0.f, 0.f, 0.f, 0.f};
  floatx4 acc[4][4];
#pragma unroll
  for (int i = 0; i < 4; i++)
#pragma unroll
    for (int j = 0; j < 4; j++) acc[i][j] = zero;

  for (int k0 = 0; k0 < 1024; k0 += 64) {
    ushort8 a0, a1, a2, a3;
    if (MODE == 0 && isf32) {
      const float* ap = arow_f + k0 + akc * 8;
      floatx4 f[8];
#pragma unroll
      for (int q = 0; q < 8; q++) f[q] = *(const floatx4*)(ap + q * 4);
#pragma unroll
      for (int i = 0; i < 4; i++) {
        a0[i] = f2bf(f[0][i]); a0[i + 4] = f2bf(f[1][i]);
        a1[i] = f2bf(f[2][i]); a1[i + 4] = f2bf(f[3][i]);
        a2[i] = f2bf(f[4][i]); a2[i + 4] = f2bf(f[5][i]);
        a3[i] = f2bf(f[6][i]); a3[i + 4] = f2bf(f[7][i]);
      }
    } else {
      const ushort_t* ap = arow_b + k0 + akc * 8;
      a0 = *(const ushort8*)(ap);
      a1 = *(const ushort8*)(ap + 8);
      a2 = *(const ushort8*)(ap + 16);
      a3 = *(const ushort8*)(ap + 24);
    }
    const ushort_t* bp = brow + k0 + akc * 8;
    ushort8 b0 = *(const ushort8*)(bp);
    ushort8 b1 = *(const ushort8*)(bp + 8);
    ushort8 b2 = *(const ushort8*)(bp + 16);
    ushort8 b3 = *(const ushort8*)(bp + 24);
    __syncthreads();
    *(ushort8*)&As[ar][akc * 8] = a0;
    *(ushort8*)&As[ar][akc * 8 + 8] = a1;
    *(ushort8*)&As[ar][akc * 8 + 16] = a2;
    *(ushort8*)&As[ar][akc * 8 + 24] = a3;
    *(ushort8*)&Bs[ar][akc * 8] = b0;
    *(ushort8*)&Bs[ar][akc * 8 + 8] = b1;
    *(ushort8*)&Bs[ar][akc * 8 + 16] = b2;
    *(ushort8*)&Bs[ar][akc * 8 + 24] = b3;
    __syncthreads();
#pragma unroll
    for (int ks = 0; ks < 2; ks++) {
      int koff = ks * 32 + qd * 8;
      bf16x8 afr[4], bfr[4];
#pragma unroll
      for (int i = 0; i < 4; i++) afr[i] = *(const bf16x8*)&As[wm + i * 16 + ln][koff];
#pragma unroll
      for (int j = 0; j < 4; j++) bfr[j] = *(const bf16x8*)&Bs[wn + j * 16 + ln][koff];
#pragma unroll
      for (int i = 0; i < 4; i++)
#pragma unroll
        for (int j = 0; j < 4; j++)
          acc[i][j] = __builtin_amdgcn_mfma_f32_16x16x32_bf16(afr[i], bfr[j], acc[i][j], 0, 0, 0);
    }
  }

  // C/D layout: col = lane&15, row = (lane>>4)*4 + reg  [m89]
#pragma unroll
  for (int i = 0; i < 4; i++) {
#pragma unroll
    for (int r = 0; r < 4; r++) {
      int rl = wm + i * 16 + qd * 4 + r;
      int gm = m0 + rl;
      if (gm >= M) continue;
      int s = srow[rl];
      float p = (MODE == 1) ? prob[s] : 0.f;
      ushort_t* orow = Out + (size_t)s * 1024 + n0 + wn + ln;
#pragma unroll
      for (int j = 0; j < 4; j++) {
        float v = acc[i][j][r];
        if (MODE == 0) { v = fmaxf(v, 0.f); v = v * v; }
        else v *= p;
        orow[j * 16] = f2bf(v);
      }
    }
  }
}

// out (FLOAT32) [t][c] = oslots[2t][c] + oslots[2t+1][c]
__global__ void combine_kernel(const ushort_t* __restrict__ oslots,
                               float* __restrict__ out) {
  int idx = (blockIdx.x * 256 + threadIdx.x) * 8;
  int t = idx >> 10;
  int c = idx & 1023;
  const ushort_t* r0 = oslots + ((size_t)t * 2) * 1024 + c;
  const ushort_t* r1 = r0 + 1024;
  ushort8 a = *(const ushort8*)r0;
  ushort8 b = *(const ushort8*)r1;
  floatx4 o0, o1;
#pragma unroll
  for (int i = 0; i < 4; i++) o0[i] = bf2f(a[i]) + bf2f(b[i]);
#pragma unroll
  for (int i = 0; i < 4; i++) o1[i] = bf2f(a[4 + i]) + bf2f(b[4 + i]);
  *(floatx4*)(out + idx) = o0;
  *(floatx4*)(out + idx + 4) = o1;
}

extern "C" void kernel_launch(void* const* d_in, const int* in_sizes, int n_in,
                              void* d_out, int out_size, void* d_ws, size_t ws_size,
                              hipStream_t stream) {
  const void* x  = d_in[0];
  const void* rw = d_in[1];
  const void* w1 = d_in[2];
  const void* w2 = d_in[3];
  float* out = (float*)d_out;
  char* ws = (char*)d_ws;

  int* cnt  = (int*)(ws + 0);                       // 32 B
  int* flag = (int*)(ws + 64);                      // 4 B
  int* slots = (int*)(ws + 1024);                   // 256 KiB
  float* prob = (float*)(ws + 263168);              // 64 KiB
  int* tok_e = (int*)(ws + 335872);                 // 32 KiB
  ushort_t* hidden = (ushort_t*)(ws + 524288);      // 32 MiB
  ushort_t* w2T = (ushort_t*)(ws + 34078720);       // 16 MiB
  ushort_t* w1T = (ushort_t*)(ws + 50855936);       // 16 MiB (dead after gemm0)
  ushort_t* oslots = (ushort_t*)(ws + 50855936);    // 32 MiB, aliases w1T
  // high-water: ~80.5 MiB

  detect_init_kernel<<<1, 128, 0, stream>>>((const ushort_t*)x, flag, cnt);
  router_compute<<<N_TOK / 4, 256, 0, stream>>>(x, rw, flag, tok_e, prob);
  scatter_kernel<<<NEXP, 1024, 0, stream>>>(tok_e, cnt, slots);
  transpose_kernel<<<dim3(16, 16, 16), 256, 0, stream>>>(w1, w2, flag, w1T, w2T);
  moe_gemm<0><<<dim3(8, 64, 8), 256, 0, stream>>>(x, w1T, hidden, cnt, slots, prob, flag);
  moe_gemm<1><<<dim3(8, 64, 8), 256, 0, stream>>>(hidden, w2T, oslots, cnt, slots, prob, flag);
  combine_kernel<<<4096, 256, 0, stream>>>(oslots, out);
}

// Round 5
// 302.128 us; speedup vs baseline: 1.7576x; 1.1872x over previous
//
#include <hip/hip_runtime.h>
#include <cstdint>
#include <cstddef>

typedef unsigned short ushort_t;
typedef unsigned short ushort8 __attribute__((ext_vector_type(8)));
typedef __bf16 bf16x8 __attribute__((ext_vector_type(8)));
typedef float floatx4 __attribute__((ext_vector_type(4)));

#define N_TOK 8192
#define CDIM 1024
#define NEXP 8

__device__ __forceinline__ float bf2f(ushort_t h) {
  union { unsigned int u; float f; } v; v.u = ((unsigned int)h) << 16; return v.f;
}
__device__ __forceinline__ ushort_t f2bf(float f) {
  union { float f; unsigned int u; } v; v.f = f;
  unsigned int r = v.u + 0x7fffu + ((v.u >> 16) & 1u);
  return (ushort_t)(r >> 16);
}

// Async global->LDS, 16B per lane. LDS dest = base + lane*16 (HW-defined).
__device__ __forceinline__ void async_copy16(const ushort_t* g, ushort_t* l) {
  __builtin_amdgcn_global_load_lds(
      (const __attribute__((address_space(1))) unsigned int*)g,
      (__attribute__((address_space(3))) unsigned int*)l, 16, 0, 0);
}

// Input-dtype probe (f32 vs bf16) + zero the expert counters.
__global__ void detect_init_kernel(const ushort_t* __restrict__ x,
                                   int* __restrict__ flag,
                                   int* __restrict__ cnt) {
  int tid = threadIdx.x;  // 128 threads
  ushort_t u = x[tid];
  int ex = (u >> 7) & 0xFF;
  int crazy = (ex >= 0xC0 || ex <= 0x30) ? 1 : 0;
  int total = __syncthreads_count(crazy);
  if (tid == 0) flag[0] = (total >= 16) ? 1 : 0;
  if (tid < NEXP) cnt[tid] = 0;
}

// x (native dtype) -> xbf (bf16), 8 elems/thread.
__global__ void convert_x_kernel(const void* __restrict__ xv,
                                 const int* __restrict__ flag,
                                 ushort_t* __restrict__ xbf) {
  int idx = (blockIdx.x * 256 + threadIdx.x) * 8;
  if (flag[0]) {
    const float* xp = (const float*)xv + idx;
    floatx4 f0 = *(const floatx4*)xp;
    floatx4 f1 = *(const floatx4*)(xp + 4);
    ushort8 o;
#pragma unroll
    for (int i = 0; i < 4; i++) { o[i] = f2bf(f0[i]); o[4 + i] = f2bf(f1[i]); }
    *(ushort8*)(xbf + idx) = o;
  } else {
    *(ushort8*)(xbf + idx) = *(const ushort8*)((const ushort_t*)xv + idx);
  }
}

// One wave per token: logits at native precision, top-2 (ties->lower idx),
// softmax over 2. NO global atomics — writes tok_e[t] and probs only.
__global__ void router_compute(const void* __restrict__ xv,
                               const void* __restrict__ rwv,
                               const int* __restrict__ flag,
                               int* __restrict__ tok_e,
                               float* __restrict__ prob) {
  int isf32 = flag[0];
  int wid = threadIdx.x >> 6;
  int lane = threadIdx.x & 63;
  int t = blockIdx.x * 4 + wid;

  float acc[NEXP];
#pragma unroll
  for (int e = 0; e < NEXP; e++) acc[e] = 0.f;

  if (isf32) {
    const float* xr = (const float*)xv + (size_t)t * CDIM;
    const float* rw = (const float*)rwv;
#pragma unroll
    for (int half = 0; half < 2; half++) {
      int base = (lane + half * 64) * 8;
      floatx4 x0 = *(const floatx4*)(xr + base);
      floatx4 x1 = *(const floatx4*)(xr + base + 4);
#pragma unroll
      for (int e = 0; e < NEXP; e++) {
        floatx4 w0 = *(const floatx4*)(rw + e * CDIM + base);
        floatx4 w1 = *(const floatx4*)(rw + e * CDIM + base + 4);
        acc[e] += x0[0]*w0[0] + x0[1]*w0[1] + x0[2]*w0[2] + x0[3]*w0[3]
                + x1[0]*w1[0] + x1[1]*w1[1] + x1[2]*w1[2] + x1[3]*w1[3];
      }
    }
  } else {
    const ushort_t* xr = (const ushort_t*)xv + (size_t)t * CDIM;
    const ushort_t* rw = (const ushort_t*)rwv;
#pragma unroll
    for (int half = 0; half < 2; half++) {
      int base = (lane + half * 64) * 8;
      ushort8 xu = *(const ushort8*)(xr + base);
#pragma unroll
      for (int e = 0; e < NEXP; e++) {
        ushort8 wu = *(const ushort8*)(rw + e * CDIM + base);
#pragma unroll
        for (int i = 0; i < 8; i++) acc[e] += bf2f(xu[i]) * bf2f(wu[i]);
      }
    }
  }

#pragma unroll
  for (int e = 0; e < NEXP; e++) {
#pragma unroll
    for (int off = 32; off > 0; off >>= 1) acc[e] += __shfl_xor(acc[e], off);
  }

  if (lane == 0) {
    int e0 = 0; float l0 = acc[0];
#pragma unroll
    for (int e = 1; e < NEXP; e++) if (acc[e] > l0) { l0 = acc[e]; e0 = e; }
    int e1 = (e0 == 0) ? 1 : 0; float l1 = acc[e1];
#pragma unroll
    for (int e = 0; e < NEXP; e++) {
      if (e != e0 && acc[e] > l1) { l1 = acc[e]; e1 = e; }
    }
    float p0 = 1.f / (1.f + __expf(l1 - l0));  // l0 = max -> stable
    tok_e[t] = e0 | (e1 << 8);
    prob[t * 2] = p0;
    prob[t * 2 + 1] = 1.f - p0;
  }
}

// Build per-expert slot lists. 8 blocks x 1024 threads, 1024 tokens/block.
__global__ void scatter_kernel(const int* __restrict__ tok_e,
                               int* __restrict__ cnt,
                               int* __restrict__ slots) {
  __shared__ int lcnt[NEXP];
  __shared__ int gbase[NEXP];
  int tid = threadIdx.x;
  if (tid < NEXP) lcnt[tid] = 0;
  __syncthreads();
  int t = blockIdx.x * 1024 + tid;
  int ee = tok_e[t];
  int e0 = ee & 0xFF, e1 = (ee >> 8) & 0xFF;
  int lofs0 = atomicAdd(&lcnt[e0], 1);
  int lofs1 = atomicAdd(&lcnt[e1], 1);
  __syncthreads();
  if (tid < NEXP) gbase[tid] = atomicAdd(&cnt[tid], lcnt[tid]);
  __syncthreads();
  slots[e0 * N_TOK + gbase[e0] + lofs0] = t * 2;
  slots[e1 * N_TOK + gbase[e1] + lofs1] = t * 2 + 1;
}

// Transpose (+convert to bf16) 1024x1024: z<8 -> w1[z], else w2[z-8].
__global__ void transpose_kernel(const void* __restrict__ w1v,
                                 const void* __restrict__ w2v,
                                 const int* __restrict__ flag,
                                 ushort_t* __restrict__ w1T,
                                 ushort_t* __restrict__ w2T) {
  int isf32 = flag[0];
  int z = blockIdx.z;
  size_t moff = (size_t)(z & 7) << 20;
  const void* srcv = (z < 8) ? w1v : w2v;
  ushort_t* dst = ((z < 8) ? w1T : w2T) + moff;

  __shared__ __align__(16) ushort_t tile[64][72];
  int t = threadIdx.x;
  int R0 = blockIdx.y * 64, C0 = blockIdx.x * 64;
  int r = t >> 2, cb = (t & 3) * 16;
  if (isf32) {
    const float* sp = (const float*)srcv + moff + (size_t)(R0 + r) * 1024 + C0 + cb;
    ushort8 o0, o1;
#pragma unroll
    for (int q = 0; q < 2; q++) {
      floatx4 f = *(const floatx4*)(sp + q * 4);
#pragma unroll
      for (int i = 0; i < 4; i++) o0[q * 4 + i] = f2bf(f[i]);
    }
#pragma unroll
    for (int q = 0; q < 2; q++) {
      floatx4 f = *(const floatx4*)(sp + 8 + q * 4);
#pragma unroll
      for (int i = 0; i < 4; i++) o1[q * 4 + i] = f2bf(f[i]);
    }
    *(ushort8*)&tile[r][cb] = o0;
    *(ushort8*)&tile[r][cb + 8] = o1;
  } else {
    const ushort_t* sp = (const ushort_t*)srcv + moff + (size_t)(R0 + r) * 1024 + C0 + cb;
    *(ushort8*)&tile[r][cb] = *(const ushort8*)sp;
    *(ushort8*)&tile[r][cb + 8] = *(const ushort8*)(sp + 8);
  }
  __syncthreads();
  int d = t >> 2, rb = (t & 3) * 16;
  ushort8 o0, o1;
#pragma unroll
  for (int j = 0; j < 8; j++) { o0[j] = tile[rb + j][d]; o1[j] = tile[rb + 8 + j][d]; }
  ushort_t* dp = dst + (size_t)(C0 + d) * 1024 + R0 + rb;
  *(ushort8*)dp = o0;
  *(ushort8*)(dp + 8) = o1;
}

// Grouped GEMM, 128x128 tile, BK=64, mfma_f32_16x16x32_bf16, 4 waves (2x2).
// m97 structure: global_load_lds width-16 staging, 2 barriers per K-iter.
// LDS unpadded [128][64] with XOR chunk swizzle (chunk ^= row&7) applied on
// the GLOBAL source address -> b128 frag reads spread over all 32 banks.
// MODE 0: hidden[slot] = relu(xbf[slot>>1] @ w1T[e]^T)^2
// MODE 1: oslots[slot] = prob[slot] * (hidden[slot] @ w2T[e]^T)
template <int MODE>
__global__ __launch_bounds__(256) void moe_gemm(const ushort_t* __restrict__ A,
                                                const ushort_t* __restrict__ BT,
                                                ushort_t* __restrict__ Out,
                                                const int* __restrict__ cnt,
                                                const int* __restrict__ slots,
                                                const float* __restrict__ prob) {
  int e = blockIdx.z;
  int M = cnt[e];
  M = (M > N_TOK) ? N_TOK : M;
  int m0 = blockIdx.y * 128;
  if (m0 >= M) return;
  int n0 = blockIdx.x * 128;

  __shared__ __align__(16) ushort_t As[128 * 64];
  __shared__ __align__(16) ushort_t Bs[128 * 64];
  __shared__ int srow[128];

  int tid = threadIdx.x;
  if (tid < 128) {
    int gm = m0 + tid;
    int gi = (gm < M) ? gm : (M - 1);
    srow[tid] = slots[e * N_TOK + gi] & (2 * N_TOK - 1);
  }
  __syncthreads();

  int wid = tid >> 6;
  int lane = tid & 63;
  int lrow = lane >> 3;              // 0..7: row within 8-row staging stripe
  int gchunk = (lane & 7) ^ lrow;    // swizzled 16B source chunk (0..7)

  // Per-thread staging source pointers: 4 stripes of 8 rows each for A and B.
  const ushort_t* aptr[4];
  const ushort_t* bptr[4];
  int rowbase = wid * 32;
#pragma unroll
  for (int j = 0; j < 4; j++) {
    int rr = rowbase + j * 8 + lrow;
    int s = srow[rr];
    int aidx = (MODE == 0) ? (s >> 1) : s;
    aptr[j] = A + (size_t)aidx * CDIM + gchunk * 8;
    bptr[j] = BT + ((size_t)e << 20) + (size_t)(n0 + rr) * 1024 + gchunk * 8;
  }
  ushort_t* albase = &As[rowbase * 64];  // wave-uniform LDS bases
  ushort_t* blbase = &Bs[rowbase * 64];

  int wm = (wid >> 1) * 64;
  int wn = (wid & 1) * 64;
  int qd = lane >> 4;
  int ln = lane & 15;
  int l7 = ln & 7;

  floatx4 zero = {0.f, 0.f, 0.f, 0.f};
  floatx4 acc[4][4];
#pragma unroll
  for (int i = 0; i < 4; i++)
#pragma unroll
    for (int j = 0; j < 4; j++) acc[i][j] = zero;

  for (int k0 = 0; k0 < 1024; k0 += 64) {
    __syncthreads();  // previous iter's LDS reads complete
#pragma unroll
    for (int j = 0; j < 4; j++) {
      async_copy16(aptr[j] + k0, albase + j * 512);
      async_copy16(bptr[j] + k0, blbase + j * 512);
    }
    __syncthreads();  // vmcnt(0) drain + barrier -> LDS ready
#pragma unroll
    for (int ks = 0; ks < 2; ks++) {
      bf16x8 afr[4], bfr[4];
#pragma unroll
      for (int i = 0; i < 4; i++) {
        int pc = ((ks * 4 + qd) ^ l7) * 8;
        afr[i] = *(const bf16x8*)&As[(wm + i * 16 + ln) * 64 + pc];
        bfr[i] = *(const bf16x8*)&Bs[(wn + i * 16 + ln) * 64 + pc];
      }
#pragma unroll
      for (int i = 0; i < 4; i++)
#pragma unroll
        for (int j = 0; j < 4; j++)
          acc[i][j] = __builtin_amdgcn_mfma_f32_16x16x32_bf16(afr[i], bfr[j], acc[i][j], 0, 0, 0);
    }
  }

  // C/D layout: col = lane&15, row = (lane>>4)*4 + reg  [m89]
#pragma unroll
  for (int i = 0; i < 4; i++) {
#pragma unroll
    for (int r = 0; r < 4; r++) {
      int rl = wm + i * 16 + qd * 4 + r;
      int gm = m0 + rl;
      if (gm >= M) continue;
      int s = srow[rl];
      float p = (MODE == 1) ? prob[s] : 0.f;
      ushort_t* orow = Out + (size_t)s * 1024 + n0 + wn + ln;
#pragma unroll
      for (int j = 0; j < 4; j++) {
        float v = acc[i][j][r];
        if (MODE == 0) { v = fmaxf(v, 0.f); v = v * v; }
        else v *= p;
        orow[j * 16] = f2bf(v);
      }
    }
  }
}

// out (FLOAT32) [t][c] = oslots[2t][c] + oslots[2t+1][c]
__global__ void combine_kernel(const ushort_t* __restrict__ oslots,
                               float* __restrict__ out) {
  int idx = (blockIdx.x * 256 + threadIdx.x) * 8;
  int t = idx >> 10;
  int c = idx & 1023;
  const ushort_t* r0 = oslots + ((size_t)t * 2) * 1024 + c;
  const ushort_t* r1 = r0 + 1024;
  ushort8 a = *(const ushort8*)r0;
  ushort8 b = *(const ushort8*)r1;
  floatx4 o0, o1;
#pragma unroll
  for (int i = 0; i < 4; i++) o0[i] = bf2f(a[i]) + bf2f(b[i]);
#pragma unroll
  for (int i = 0; i < 4; i++) o1[i] = bf2f(a[4 + i]) + bf2f(b[4 + i]);
  *(floatx4*)(out + idx) = o0;
  *(floatx4*)(out + idx + 4) = o1;
}

extern "C" void kernel_launch(void* const* d_in, const int* in_sizes, int n_in,
                              void* d_out, int out_size, void* d_ws, size_t ws_size,
                              hipStream_t stream) {
  const void* x  = d_in[0];
  const void* rw = d_in[1];
  const void* w1 = d_in[2];
  const void* w2 = d_in[3];
  float* out = (float*)d_out;
  char* ws = (char*)d_ws;

  int* cnt  = (int*)(ws + 0);                       // 32 B
  int* flag = (int*)(ws + 64);                      // 4 B
  int* slots = (int*)(ws + 1024);                   // 256 KiB
  float* prob = (float*)(ws + 263168);              // 64 KiB
  int* tok_e = (int*)(ws + 335872);                 // 32 KiB
  ushort_t* xbf = (ushort_t*)(ws + 524288);         // 16 MiB (dead after gemm0)
  ushort_t* w1T = (ushort_t*)(ws + 17301504);       // 16 MiB (dead after gemm0)
  ushort_t* hidden = (ushort_t*)(ws + 34078720);    // 32 MiB
  ushort_t* w2T = (ushort_t*)(ws + 67633152);       // 16 MiB -> high-water 84,410,368
  ushort_t* oslots = (ushort_t*)(ws + 524288);      // 32 MiB, aliases xbf+w1T

  detect_init_kernel<<<1, 128, 0, stream>>>((const ushort_t*)x, flag, cnt);
  router_compute<<<N_TOK / 4, 256, 0, stream>>>(x, rw, flag, tok_e, prob);
  scatter_kernel<<<NEXP, 1024, 0, stream>>>(tok_e, cnt, slots);
  convert_x_kernel<<<4096, 256, 0, stream>>>(x, flag, xbf);
  transpose_kernel<<<dim3(16, 16, 16), 256, 0, stream>>>(w1, w2, flag, w1T, w2T);
  moe_gemm<0><<<dim3(8, 64, 8), 256, 0, stream>>>(xbf, w1T, hidden, cnt, slots, prob);
  moe_gemm<1><<<dim3(8, 64, 8), 256, 0, stream>>>(hidden, w2T, oslots, cnt, slots, prob);
  combine_kernel<<<4096, 256, 0, stream>>>(oslots, out);
}

// Round 6
// 274.324 us; speedup vs baseline: 1.9357x; 1.1014x over previous
//
#include <hip/hip_runtime.h>
#include <cstdint>
#include <cstddef>

typedef unsigned short ushort_t;
typedef unsigned short ushort8 __attribute__((ext_vector_type(8)));
typedef __bf16 bf16x8 __attribute__((ext_vector_type(8)));
typedef float floatx4 __attribute__((ext_vector_type(4)));

#define N_TOK 8192
#define CDIM 1024
#define NEXP 8

__device__ __forceinline__ float bf2f(ushort_t h) {
  union { unsigned int u; float f; } v; v.u = ((unsigned int)h) << 16; return v.f;
}
__device__ __forceinline__ ushort_t f2bf(float f) {
  union { float f; unsigned int u; } v; v.f = f;
  unsigned int r = v.u + 0x7fffu + ((v.u >> 16) & 1u);
  return (ushort_t)(r >> 16);
}

// Async global->LDS, 16B per lane. LDS dest = base + lane*16 (HW-defined).
__device__ __forceinline__ void async_copy16(const ushort_t* g, ushort_t* l) {
  __builtin_amdgcn_global_load_lds(
      (const __attribute__((address_space(1))) unsigned int*)g,
      (__attribute__((address_space(3))) unsigned int*)l, 16, 0, 0);
}

// Input-dtype probe (f32 vs bf16) + zero the expert counters.
__global__ void detect_init_kernel(const ushort_t* __restrict__ x,
                                   int* __restrict__ flag,
                                   int* __restrict__ cnt) {
  int tid = threadIdx.x;  // 128 threads
  ushort_t u = x[tid];
  int ex = (u >> 7) & 0xFF;
  int crazy = (ex >= 0xC0 || ex <= 0x30) ? 1 : 0;
  int total = __syncthreads_count(crazy);
  if (tid == 0) flag[0] = (total >= 16) ? 1 : 0;
  if (tid < NEXP) cnt[tid] = 0;
}

// One wave per token: logits at native precision, top-2 (ties->lower idx),
// softmax over 2. Also emits the token row converted to bf16 (xbf) —
// the wave touches every element of the row anyway.
__global__ void router_compute(const void* __restrict__ xv,
                               const void* __restrict__ rwv,
                               const int* __restrict__ flag,
                               int* __restrict__ tok_e,
                               float* __restrict__ prob,
                               ushort_t* __restrict__ xbf) {
  int isf32 = flag[0];
  int wid = threadIdx.x >> 6;
  int lane = threadIdx.x & 63;
  int t = blockIdx.x * 4 + wid;

  float acc[NEXP];
#pragma unroll
  for (int e = 0; e < NEXP; e++) acc[e] = 0.f;

  if (isf32) {
    const float* xr = (const float*)xv + (size_t)t * CDIM;
    const float* rw = (const float*)rwv;
#pragma unroll
    for (int half = 0; half < 2; half++) {
      int base = (lane + half * 64) * 8;
      floatx4 x0 = *(const floatx4*)(xr + base);
      floatx4 x1 = *(const floatx4*)(xr + base + 4);
      ushort8 o;
#pragma unroll
      for (int i = 0; i < 4; i++) { o[i] = f2bf(x0[i]); o[4 + i] = f2bf(x1[i]); }
      *(ushort8*)(xbf + (size_t)t * CDIM + base) = o;
#pragma unroll
      for (int e = 0; e < NEXP; e++) {
        floatx4 w0 = *(const floatx4*)(rw + e * CDIM + base);
        floatx4 w1 = *(const floatx4*)(rw + e * CDIM + base + 4);
        acc[e] += x0[0]*w0[0] + x0[1]*w0[1] + x0[2]*w0[2] + x0[3]*w0[3]
                + x1[0]*w1[0] + x1[1]*w1[1] + x1[2]*w1[2] + x1[3]*w1[3];
      }
    }
  } else {
    const ushort_t* xr = (const ushort_t*)xv + (size_t)t * CDIM;
    const ushort_t* rw = (const ushort_t*)rwv;
#pragma unroll
    for (int half = 0; half < 2; half++) {
      int base = (lane + half * 64) * 8;
      ushort8 xu = *(const ushort8*)(xr + base);
      *(ushort8*)(xbf + (size_t)t * CDIM + base) = xu;
#pragma unroll
      for (int e = 0; e < NEXP; e++) {
        ushort8 wu = *(const ushort8*)(rw + e * CDIM + base);
#pragma unroll
        for (int i = 0; i < 8; i++) acc[e] += bf2f(xu[i]) * bf2f(wu[i]);
      }
    }
  }

#pragma unroll
  for (int e = 0; e < NEXP; e++) {
#pragma unroll
    for (int off = 32; off > 0; off >>= 1) acc[e] += __shfl_xor(acc[e], off);
  }

  if (lane == 0) {
    int e0 = 0; float l0 = acc[0];
#pragma unroll
    for (int e = 1; e < NEXP; e++) if (acc[e] > l0) { l0 = acc[e]; e0 = e; }
    int e1 = (e0 == 0) ? 1 : 0; float l1 = acc[e1];
#pragma unroll
    for (int e = 0; e < NEXP; e++) {
      if (e != e0 && acc[e] > l1) { l1 = acc[e]; e1 = e; }
    }
    float p0 = 1.f / (1.f + __expf(l1 - l0));  // l0 = max -> stable
    tok_e[t] = e0 | (e1 << 8);
    prob[t * 2] = p0;
    prob[t * 2 + 1] = 1.f - p0;
  }
}

// Build per-expert slot lists. 8 blocks x 1024 threads, 1024 tokens/block.
__global__ void scatter_kernel(const int* __restrict__ tok_e,
                               int* __restrict__ cnt,
                               int* __restrict__ slots) {
  __shared__ int lcnt[NEXP];
  __shared__ int gbase[NEXP];
  int tid = threadIdx.x;
  if (tid < NEXP) lcnt[tid] = 0;
  __syncthreads();
  int t = blockIdx.x * 1024 + tid;
  int ee = tok_e[t];
  int e0 = ee & 0xFF, e1 = (ee >> 8) & 0xFF;
  int lofs0 = atomicAdd(&lcnt[e0], 1);
  int lofs1 = atomicAdd(&lcnt[e1], 1);
  __syncthreads();
  if (tid < NEXP) gbase[tid] = atomicAdd(&cnt[tid], lcnt[tid]);
  __syncthreads();
  slots[e0 * N_TOK + gbase[e0] + lofs0] = t * 2;
  slots[e1 * N_TOK + gbase[e1] + lofs1] = t * 2 + 1;
}

// Transpose (+convert to bf16) 1024x1024: z<8 -> w1[z], else w2[z-8].
__global__ void transpose_kernel(const void* __restrict__ w1v,
                                 const void* __restrict__ w2v,
                                 const int* __restrict__ flag,
                                 ushort_t* __restrict__ w1T,
                                 ushort_t* __restrict__ w2T) {
  int isf32 = flag[0];
  int z = blockIdx.z;
  size_t moff = (size_t)(z & 7) << 20;
  const void* srcv = (z < 8) ? w1v : w2v;
  ushort_t* dst = ((z < 8) ? w1T : w2T) + moff;

  __shared__ __align__(16) ushort_t tile[64][72];
  int t = threadIdx.x;
  int R0 = blockIdx.y * 64, C0 = blockIdx.x * 64;
  int r = t >> 2, cb = (t & 3) * 16;
  if (isf32) {
    const float* sp = (const float*)srcv + moff + (size_t)(R0 + r) * 1024 + C0 + cb;
    ushort8 o0, o1;
#pragma unroll
    for (int q = 0; q < 2; q++) {
      floatx4 f = *(const floatx4*)(sp + q * 4);
#pragma unroll
      for (int i = 0; i < 4; i++) o0[q * 4 + i] = f2bf(f[i]);
    }
#pragma unroll
    for (int q = 0; q < 2; q++) {
      floatx4 f = *(const floatx4*)(sp + 8 + q * 4);
#pragma unroll
      for (int i = 0; i < 4; i++) o1[q * 4 + i] = f2bf(f[i]);
    }
    *(ushort8*)&tile[r][cb] = o0;
    *(ushort8*)&tile[r][cb + 8] = o1;
  } else {
    const ushort_t* sp = (const ushort_t*)srcv + moff + (size_t)(R0 + r) * 1024 + C0 + cb;
    *(ushort8*)&tile[r][cb] = *(const ushort8*)sp;
    *(ushort8*)&tile[r][cb + 8] = *(const ushort8*)(sp + 8);
  }
  __syncthreads();
  int d = t >> 2, rb = (t & 3) * 16;
  ushort8 o0, o1;
#pragma unroll
  for (int j = 0; j < 8; j++) { o0[j] = tile[rb + j][d]; o1[j] = tile[rb + 8 + j][d]; }
  ushort_t* dp = dst + (size_t)(C0 + d) * 1024 + R0 + rb;
  *(ushort8*)dp = o0;
  *(ushort8*)(dp + 8) = o1;
}

// Grouped GEMM, 256x128 tile, BK=64, 512 threads = 8 waves (4m x 2n of 64x64).
// global_load_lds width-16 staging, XOR chunk swizzle on the global source.
// 1-D grid, expert = bid&7 -> under round-robin block->XCD mapping each XCD
// works one expert, keeping its 2 MB B-panel L2-resident. mt is the slow
// index so dead tail blocks dispatch last.
// MODE 0: hidden[slot] = relu(xbf[slot>>1] @ w1T[e]^T)^2
// MODE 1: oslots[slot] = prob[slot] * (hidden[slot] @ w2T[e]^T)
template <int MODE>
__global__ __launch_bounds__(512, 4) void moe_gemm(const ushort_t* __restrict__ A,
                                                   const ushort_t* __restrict__ BT,
                                                   ushort_t* __restrict__ Out,
                                                   const int* __restrict__ cnt,
                                                   const int* __restrict__ slots,
                                                   const float* __restrict__ prob) {
  int bid = blockIdx.x;
  int e = bid & 7;
  int nt = (bid >> 3) & 7;
  int mt = bid >> 6;
  int M = cnt[e];
  M = (M > N_TOK) ? N_TOK : M;
  int m0 = mt * 256;
  if (m0 >= M) return;
  int n0 = nt * 128;

  __shared__ __align__(16) ushort_t As[256 * 64];
  __shared__ __align__(16) ushort_t Bs[128 * 64];
  __shared__ int srow[256];

  int tid = threadIdx.x;
  if (tid < 256) {
    int gm = m0 + tid;
    int gi = (gm < M) ? gm : (M - 1);
    srow[tid] = slots[e * N_TOK + gi] & (2 * N_TOK - 1);
  }
  __syncthreads();

  int wid = tid >> 6;
  int lane = tid & 63;
  int lrow = lane >> 3;              // 0..7: row within 8-row staging stripe
  int gchunk = (lane & 7) ^ lrow;    // swizzled 16B source chunk (0..7)

  // A: 4 stripes of 8 rows per wave (256 rows). B: 2 stripes (128 rows).
  const ushort_t* aptr[4];
  const ushort_t* bptr[2];
  int arowbase = wid * 32;
  int browbase = wid * 16;
#pragma unroll
  for (int j = 0; j < 4; j++) {
    int rr = arowbase + j * 8 + lrow;
    int s = srow[rr];
    int aidx = (MODE == 0) ? (s >> 1) : s;
    aptr[j] = A + (size_t)aidx * CDIM + gchunk * 8;
  }
#pragma unroll
  for (int j = 0; j < 2; j++) {
    int rr = browbase + j * 8 + lrow;
    bptr[j] = BT + ((size_t)e << 20) + (size_t)(n0 + rr) * 1024 + gchunk * 8;
  }
  ushort_t* albase = &As[arowbase * 64];  // wave-uniform LDS bases
  ushort_t* blbase = &Bs[browbase * 64];

  int wm = (wid >> 1) * 64;   // 0,64,128,192
  int wn = (wid & 1) * 64;    // 0,64
  int qd = lane >> 4;
  int ln = lane & 15;
  int l7 = ln & 7;

  floatx4 zero = {0.f, 0.f, 0.f, 0.f};
  floatx4 acc[4][4];
#pragma unroll
  for (int i = 0; i < 4; i++)
#pragma unroll
    for (int j = 0; j < 4; j++) acc[i][j] = zero;

  for (int k0 = 0; k0 < 1024; k0 += 64) {
    __syncthreads();  // previous iter's LDS reads complete
#pragma unroll
    for (int j = 0; j < 4; j++) async_copy16(aptr[j] + k0, albase + j * 512);
#pragma unroll
    for (int j = 0; j < 2; j++) async_copy16(bptr[j] + k0, blbase + j * 512);
    __syncthreads();  // vmcnt(0) drain + barrier -> LDS ready
#pragma unroll
    for (int ks = 0; ks < 2; ks++) {
      bf16x8 afr[4], bfr[4];
#pragma unroll
      for (int i = 0; i < 4; i++) {
        int pc = ((ks * 4 + qd) ^ l7) * 8;
        afr[i] = *(const bf16x8*)&As[(wm + i * 16 + ln) * 64 + pc];
        bfr[i] = *(const bf16x8*)&Bs[(wn + i * 16 + ln) * 64 + pc];
      }
#pragma unroll
      for (int i = 0; i < 4; i++)
#pragma unroll
        for (int j = 0; j < 4; j++)
          acc[i][j] = __builtin_amdgcn_mfma_f32_16x16x32_bf16(afr[i], bfr[j], acc[i][j], 0, 0, 0);
    }
  }

  // C/D layout: col = lane&15, row = (lane>>4)*4 + reg  [m89]
#pragma unroll
  for (int i = 0; i < 4; i++) {
#pragma unroll
    for (int r = 0; r < 4; r++) {
      int rl = wm + i * 16 + qd * 4 + r;
      int gm = m0 + rl;
      if (gm >= M) continue;
      int s = srow[rl];
      float p = (MODE == 1) ? prob[s] : 0.f;
      ushort_t* orow = Out + (size_t)s * 1024 + n0 + wn + ln;
#pragma unroll
      for (int j = 0; j < 4; j++) {
        float v = acc[i][j][r];
        if (MODE == 0) { v = fmaxf(v, 0.f); v = v * v; }
        else v *= p;
        orow[j * 16] = f2bf(v);
      }
    }
  }
}

// out (FLOAT32) [t][c] = oslots[2t][c] + oslots[2t+1][c]
__global__ void combine_kernel(const ushort_t* __restrict__ oslots,
                               float* __restrict__ out) {
  int idx = (blockIdx.x * 256 + threadIdx.x) * 8;
  int t = idx >> 10;
  int c = idx & 1023;
  const ushort_t* r0 = oslots + ((size_t)t * 2) * 1024 + c;
  const ushort_t* r1 = r0 + 1024;
  ushort8 a = *(const ushort8*)r0;
  ushort8 b = *(const ushort8*)r1;
  floatx4 o0, o1;
#pragma unroll
  for (int i = 0; i < 4; i++) o0[i] = bf2f(a[i]) + bf2f(b[i]);
#pragma unroll
  for (int i = 0; i < 4; i++) o1[i] = bf2f(a[4 + i]) + bf2f(b[4 + i]);
  *(floatx4*)(out + idx) = o0;
  *(floatx4*)(out + idx + 4) = o1;
}

extern "C" void kernel_launch(void* const* d_in, const int* in_sizes, int n_in,
                              void* d_out, int out_size, void* d_ws, size_t ws_size,
                              hipStream_t stream) {
  const void* x  = d_in[0];
  const void* rw = d_in[1];
  const void* w1 = d_in[2];
  const void* w2 = d_in[3];
  float* out = (float*)d_out;
  char* ws = (char*)d_ws;

  int* cnt  = (int*)(ws + 0);                       // 32 B
  int* flag = (int*)(ws + 64);                      // 4 B
  int* slots = (int*)(ws + 1024);                   // 256 KiB
  float* prob = (float*)(ws + 263168);              // 64 KiB
  int* tok_e = (int*)(ws + 335872);                 // 32 KiB
  ushort_t* xbf = (ushort_t*)(ws + 524288);         // 16 MiB (dead after gemm0)
  ushort_t* w1T = (ushort_t*)(ws + 17301504);       // 16 MiB (dead after gemm0)
  ushort_t* hidden = (ushort_t*)(ws + 34078720);    // 32 MiB
  ushort_t* w2T = (ushort_t*)(ws + 67633152);       // 16 MiB -> high-water 84,410,368
  ushort_t* oslots = (ushort_t*)(ws + 524288);      // 32 MiB, aliases xbf+w1T

  detect_init_kernel<<<1, 128, 0, stream>>>((const ushort_t*)x, flag, cnt);
  router_compute<<<N_TOK / 4, 256, 0, stream>>>(x, rw, flag, tok_e, prob, xbf);
  scatter_kernel<<<NEXP, 1024, 0, stream>>>(tok_e, cnt, slots);
  transpose_kernel<<<dim3(16, 16, 16), 256, 0, stream>>>(w1, w2, flag, w1T, w2T);
  // grid: 32 m-tiles x 8 n-tiles x 8 experts, expert fastest (XCD affinity)
  moe_gemm<0><<<2048, 512, 0, stream>>>(xbf, w1T, hidden, cnt, slots, prob);
  moe_gemm<1><<<2048, 512, 0, stream>>>(hidden, w2T, oslots, cnt, slots, prob);
  combine_kernel<<<4096, 256, 0, stream>>>(oslots, out);
}